// Round 4
// baseline (277.921 us; speedup 1.0000x reference)
//
#include <hip/hip_runtime.h>
#include <hip/hip_bf16.h>

typedef __attribute__((ext_vector_type(8))) short short8;
typedef __attribute__((ext_vector_type(4))) float f32x4;

constexpr int N = 1024, M = 1024, D = 64, BH = 128;
constexpr size_t ATTN_ELEMS = (size_t)BH * N * M;     // 134217728
constexpr size_t QKV_ELEMS  = (size_t)BH * N * D;     // 8388608
constexpr int PB_BLOCKS = 2048;
constexpr int COPY_BLOCKS_PER = 256;                   // per q/k/v tensor
constexpr int BGROUP = 8;                              // batches per attn block

__device__ __forceinline__ short f2b(float x) {
    __hip_bfloat16 h = __float2bfloat16(x);
    return *reinterpret_cast<short*>(&h);
}

// k1: pb[n*M+m] = dot(pos_enc[0,n,m,:], w) + b  (16 lanes per (n,m), float4 each)
__global__ void pb_kernel(const float* __restrict__ pos, const float* __restrict__ w,
                          const float* __restrict__ b, float* __restrict__ pb) {
    const int lane16 = threadIdx.x & 15;
    const f32x4 w4 = ((const f32x4*)w)[lane16];
    const float bias = b[0];
    const int group = (blockIdx.x * 256 + threadIdx.x) >> 4;
    const int ngroups = (PB_BLOCKS * 256) >> 4;
    for (int pair = group; pair < N * M; pair += ngroups) {
        f32x4 p = ((const f32x4*)pos)[(size_t)pair * 16 + lane16];
        float s = p[0]*w4[0] + p[1]*w4[1] + p[2]*w4[2] + p[3]*w4[3];
        s += __shfl_xor(s, 1);
        s += __shfl_xor(s, 2);
        s += __shfl_xor(s, 4);
        s += __shfl_xor(s, 8);
        if (lane16 == 0) pb[pair] = s + bias;
    }
}

// k2: blocks [0, ncopy) do q/k/v pass-through copies; blocks [ncopy, +2048) do
// attn = (K K^T)*scale + pb with pb fragments held in registers across BGROUP
// batches. scale = sum(w)/4 computed in-register per wave (no dependency).
__launch_bounds__(256)
__global__ void attn_fused_kernel(const float* __restrict__ q, const float* __restrict__ keys,
                                  const float* __restrict__ v, const float* __restrict__ pos_w,
                                  const float* __restrict__ pb, float* __restrict__ out,
                                  float* __restrict__ qout, float* __restrict__ kout,
                                  float* __restrict__ vout, int ncopy) {
    __shared__ short lK[192 * 64];                // A: rows 0..127, B: rows 128..191
    const int bid = blockIdx.x, tid = threadIdx.x;

    if (bid < ncopy) {
        const int which = bid >> 8, lid = bid & 255;
        const f32x4* __restrict__ src = (which == 0) ? (const f32x4*)q
                                      : (which == 1) ? (const f32x4*)keys : (const f32x4*)v;
        f32x4* __restrict__ dst = (which == 0) ? (f32x4*)qout
                                : (which == 1) ? (f32x4*)kout : (f32x4*)vout;
        const int nel4 = (int)(QKV_ELEMS / 4);
        for (int i = lid * 256 + tid; i < nel4; i += COPY_BLOCKS_PER * 256) {
            dst[i] = src[i];
        }
        return;
    }

    const int abid = bid - ncopy;                 // 0..2047
    const int tr = (abid >> 4) >> 4, tc = (abid >> 4) & 15;   // tile position 0..127
    const int batch0 = (abid & 15) * BGROUP;
    const int lane = tid & 63, wv = tid >> 6;     // 4 waves
    const int wr = wv >> 1, wc = wv & 1;          // 2x2 waves of 64x32
    const int frow = lane & 15;
    const int kslot = lane >> 4;

    // scale = sum(w_pos)/sqrt(16), computed redundantly per wave.
    float sw = pos_w[lane];
#pragma unroll
    for (int o = 32; o > 0; o >>= 1) sw += __shfl_xor(sw, o);
    const float scale = sw * 0.25f;

    const int r0 = tr * 128 + wr * 64;
    const int c0 = tc * 64 + wc * 32;
    const int ocol = c0 + (lane & 15);
    const int orow = r0 + (lane >> 4) * 4;

    // pb fragments in accumulator layout — reused for all BGROUP batches.
    f32x4 pf[4][2];
#pragma unroll
    for (int i = 0; i < 4; i++)
#pragma unroll
        for (int j = 0; j < 2; j++)
#pragma unroll
            for (int r = 0; r < 4; r++)
                pf[i][j][r] = pb[(size_t)(orow + i * 16 + r) * M + (ocol + j * 16)];

    for (int t = 0; t < BGROUP; ++t) {
        const float* __restrict__ Kb = keys + (size_t)(batch0 + t) * N * D;

        // Stage A rows [tr*128,+128) and B rows [tc*64,+64), fp32 -> bf16,
        // 16B slots XOR-swizzled by (row&7).
#pragma unroll
        for (int it = 0; it < 6; ++it) {
            const int slot = it * 256 + tid;      // 0..1535
            const int row = slot >> 3, s16 = slot & 7;
            const int gr = (row < 128) ? (tr * 128 + row) : (tc * 64 + (row - 128));
            const f32x4* src = (const f32x4*)(Kb + (size_t)gr * D + s16 * 8);
            f32x4 x0 = src[0], x1 = src[1];
            short8 pk;
#pragma unroll
            for (int e = 0; e < 4; e++) { pk[e] = f2b(x0[e]); pk[4 + e] = f2b(x1[e]); }
            *(short8*)&lK[row * 64 + (s16 ^ (row & 7)) * 8] = pk;
        }
        __syncthreads();

        f32x4 acc[4][2] = {};
#pragma unroll
        for (int h = 0; h < 2; ++h) {             // k halves (k=0..31, 32..63)
            short8 a[4], bf[2];
#pragma unroll
            for (int i = 0; i < 4; i++) {
                const int ra = wr * 64 + i * 16 + frow;
                a[i] = *(const short8*)&lK[ra * 64 + ((h * 4 + kslot) ^ (ra & 7)) * 8];
            }
#pragma unroll
            for (int j = 0; j < 2; j++) {
                const int rb = 128 + wc * 32 + j * 16 + frow;
                bf[j] = *(const short8*)&lK[rb * 64 + ((h * 4 + kslot) ^ (rb & 7)) * 8];
            }
#pragma unroll
            for (int i = 0; i < 4; i++)
#pragma unroll
                for (int j = 0; j < 2; j++)
                    acc[i][j] = __builtin_amdgcn_mfma_f32_16x16x32_bf16(a[i], bf[j], acc[i][j], 0, 0, 0);
        }

        const size_t obase = (size_t)(batch0 + t) * N * M;
#pragma unroll
        for (int i = 0; i < 4; i++)
#pragma unroll
            for (int j = 0; j < 2; j++)
#pragma unroll
                for (int r = 0; r < 4; r++) {
                    out[obase + (size_t)(orow + i * 16 + r) * M + (ocol + j * 16)]
                        = acc[i][j][r] * scale + pf[i][j][r];
                }
        __syncthreads();                          // LDS safe to overwrite next t
    }
}

extern "C" void kernel_launch(void* const* d_in, const int* in_sizes, int n_in,
                              void* d_out, int out_size, void* d_ws, size_t ws_size,
                              hipStream_t stream) {
    const float* queries = (const float*)d_in[0];
    const float* keys    = (const float*)d_in[1];
    const float* values  = (const float*)d_in[2];
    const float* pos_enc = (const float*)d_in[3];
    const float* w_pos   = (const float*)d_in[4];
    const float* b_pos   = (const float*)d_in[5];

    float* out  = (float*)d_out;
    float* qout = out + ATTN_ELEMS;
    float* kout = qout + QKV_ELEMS;
    float* vout = kout + QKV_ELEMS;

    const bool use_ws = ws_size >= ((size_t)N * M + 16) * sizeof(float);

    if (use_ws) {
        float* pb = (float*)d_ws;
        const int ncopy = 3 * COPY_BLOCKS_PER;
        pb_kernel<<<dim3(PB_BLOCKS), dim3(256), 0, stream>>>(pos_enc, w_pos, b_pos, pb);
        attn_fused_kernel<<<dim3(ncopy + 2048), dim3(256), 0, stream>>>(
            queries, keys, values, w_pos, pb, out, qout, kout, vout, ncopy);
    } else {
        // Fallback: pb lives in the q-region of d_out; copies must come AFTER attn.
        float* pb = qout;
        pb_kernel<<<dim3(PB_BLOCKS), dim3(256), 0, stream>>>(pos_enc, w_pos, b_pos, pb);
        attn_fused_kernel<<<dim3(2048), dim3(256), 0, stream>>>(
            queries, keys, values, w_pos, pb, out, qout, kout, vout, /*ncopy=*/0);
        hipMemcpyAsync(qout, queries, QKV_ELEMS * sizeof(float), hipMemcpyDeviceToDevice, stream);
        hipMemcpyAsync(kout, keys,    QKV_ELEMS * sizeof(float), hipMemcpyDeviceToDevice, stream);
        hipMemcpyAsync(vout, values,  QKV_ELEMS * sizeof(float), hipMemcpyDeviceToDevice, stream);
    }
}

// Round 5
// 256.298 us; speedup vs baseline: 1.0844x; 1.0844x over previous
//
#include <hip/hip_runtime.h>
#include <hip/hip_bf16.h>

typedef __attribute__((ext_vector_type(8))) short short8;
typedef __attribute__((ext_vector_type(4))) float f32x4;

constexpr int N = 1024, M = 1024, D = 64, BH = 128;
constexpr size_t ATTN_ELEMS = (size_t)BH * N * M;     // 134217728
constexpr size_t QKV_ELEMS  = (size_t)BH * N * D;     // 8388608
constexpr int PB_BLOCKS = 2048;
constexpr int COPY_BLOCKS_PER = 256;                   // per q/k/v tensor
constexpr int BGROUP = 8;                              // batches per attn block
constexpr int BR = 32, BC = 256;                       // attn tile: 32 rows x 256 cols

__device__ __forceinline__ short f2b(float x) {
    __hip_bfloat16 h = __float2bfloat16(x);
    return *reinterpret_cast<short*>(&h);
}

// Fused prep (r3 structure, unchanged — it measured fine):
//   blocks [0, PB_BLOCKS)               : pb[n,m] = pos_enc[n,m,:].w + b
//   blocks [PB_BLOCKS, PB_BLOCKS+ncopy) : q/k/v pass-through copies
//   last block                          : scale = sum(w)/sqrt(16)
__global__ void prep_kernel(const float* __restrict__ q, const float* __restrict__ k,
                            const float* __restrict__ v, const float* __restrict__ pos,
                            const float* __restrict__ w, const float* __restrict__ b,
                            float* __restrict__ pb, float* __restrict__ scale_p,
                            float* __restrict__ qout, float* __restrict__ kout,
                            float* __restrict__ vout, int ncopy) {
    const int bid = blockIdx.x, tid = threadIdx.x;
    if (bid < PB_BLOCKS) {
        const int lane16 = tid & 15;
        const f32x4 w4 = ((const f32x4*)w)[lane16];
        const float bias = b[0];
        const int group = (bid * 256 + tid) >> 4;
        const int ngroups = (PB_BLOCKS * 256) >> 4;
        for (int pair = group; pair < N * M; pair += ngroups) {
            f32x4 p = __builtin_nontemporal_load((const f32x4*)pos + (size_t)pair * 16 + lane16);
            float s = p[0]*w4[0] + p[1]*w4[1] + p[2]*w4[2] + p[3]*w4[3];
            s += __shfl_xor(s, 1);
            s += __shfl_xor(s, 2);
            s += __shfl_xor(s, 4);
            s += __shfl_xor(s, 8);
            if (lane16 == 0) pb[pair] = s + bias;
        }
    } else if (bid < PB_BLOCKS + ncopy) {
        const int cid = bid - PB_BLOCKS;
        const int which = cid >> 8, lid = cid & 255;
        const f32x4* __restrict__ src = (which == 0) ? (const f32x4*)q
                                      : (which == 1) ? (const f32x4*)k : (const f32x4*)v;
        f32x4* __restrict__ dst = (which == 0) ? (f32x4*)qout
                                : (which == 1) ? (f32x4*)kout : (f32x4*)vout;
        const int nel4 = (int)(QKV_ELEMS / 4);
        for (int i = lid * 256 + tid; i < nel4; i += COPY_BLOCKS_PER * 256) {
            f32x4 x = __builtin_nontemporal_load(src + i);
            __builtin_nontemporal_store(x, dst + i);
        }
    } else {
        if (tid < 64) {
            float val = w[tid];
#pragma unroll
            for (int o = 32; o > 0; o >>= 1) val += __shfl_down(val, o);
            if (tid == 0) scale_p[0] = val * 0.25f;
        }
    }
}

// attn = (K K^T)*scale + pb.  Tile reshaped to 32 rows x 256 cols so each
// block writes 1KB-contiguous chunks per output row (write locality).
// 4 waves (2x2): each wave 16 rows x 128 cols.  BGROUP batches per block with
// pb fragments held in registers.  LDS: A rows 0..31, B rows 32..287 (36KB).
__launch_bounds__(256)
__global__ void attn_kernel(const float* __restrict__ keys, const float* __restrict__ pb,
                            const float* __restrict__ scale_p, float* __restrict__ out) {
    __shared__ short lK[(BR + BC) * 64];
    const int pos = blockIdx.x;                   // 0..127
    const int tr = pos >> 2, tc = pos & 3;        // 32 row-tiles x 4 col-tiles
    const int batch0 = blockIdx.y * BGROUP;
    const int tid = threadIdx.x;
    const float scale = scale_p[0];

    const int lane = tid & 63, wv = tid >> 6;     // 4 waves
    const int wr = wv >> 1, wc = wv & 1;          // 2x2: 16 rows x 128 cols each
    const int frow = lane & 15;
    const int kslot = lane >> 4;

    const int orow = tr * BR + wr * 16 + (lane >> 4) * 4;   // + r
    const int ocol = tc * BC + wc * 128 + (lane & 15);      // + j*16

    // pb fragments in accumulator layout — reused for all BGROUP batches.
    f32x4 pf[8];
#pragma unroll
    for (int j = 0; j < 8; j++)
#pragma unroll
        for (int r = 0; r < 4; r++)
            pf[j][r] = pb[(size_t)(orow + r) * M + (ocol + j * 16)];

    for (int t = 0; t < BGROUP; ++t) {
        const float* __restrict__ Kb = keys + (size_t)(batch0 + t) * N * D;

        // Stage A rows [tr*32,+32) and B rows [tc*256,+256), fp32 -> bf16,
        // 16B slots XOR-swizzled by (row&7).  288 rows * 8 slots = 2304.
#pragma unroll
        for (int it = 0; it < 9; ++it) {
            const int slot = it * 256 + tid;
            const int row = slot >> 3, s16 = slot & 7;
            const int gr = (row < BR) ? (tr * BR + row) : (tc * BC + (row - BR));
            const f32x4* src = (const f32x4*)(Kb + (size_t)gr * D + s16 * 8);
            f32x4 x0 = src[0], x1 = src[1];
            short8 pk;
#pragma unroll
            for (int e = 0; e < 4; e++) { pk[e] = f2b(x0[e]); pk[4 + e] = f2b(x1[e]); }
            *(short8*)&lK[row * 64 + (s16 ^ (row & 7)) * 8] = pk;
        }
        __syncthreads();

        f32x4 acc[8] = {};
#pragma unroll
        for (int h = 0; h < 2; ++h) {             // k halves (k=0..31, 32..63)
            const int ra = wr * 16 + frow;
            short8 a = *(const short8*)&lK[ra * 64 + ((h * 4 + kslot) ^ (ra & 7)) * 8];
#pragma unroll
            for (int j = 0; j < 8; j++) {
                const int rb = BR + wc * 128 + j * 16 + frow;
                short8 bf = *(const short8*)&lK[rb * 64 + ((h * 4 + kslot) ^ (rb & 7)) * 8];
                acc[j] = __builtin_amdgcn_mfma_f32_16x16x32_bf16(a, bf, acc[j], 0, 0, 0);
            }
        }

        const size_t obase = (size_t)(batch0 + t) * N * M;
#pragma unroll
        for (int j = 0; j < 8; j++)
#pragma unroll
            for (int r = 0; r < 4; r++) {
                out[obase + (size_t)(orow + r) * M + (ocol + j * 16)]
                    = acc[j][r] * scale + pf[j][r];
            }
        __syncthreads();                          // LDS safe to overwrite next t
    }
}

extern "C" void kernel_launch(void* const* d_in, const int* in_sizes, int n_in,
                              void* d_out, int out_size, void* d_ws, size_t ws_size,
                              hipStream_t stream) {
    const float* queries = (const float*)d_in[0];
    const float* keys    = (const float*)d_in[1];
    const float* values  = (const float*)d_in[2];
    const float* pos_enc = (const float*)d_in[3];
    const float* w_pos   = (const float*)d_in[4];
    const float* b_pos   = (const float*)d_in[5];

    float* out  = (float*)d_out;
    float* qout = out + ATTN_ELEMS;
    float* kout = qout + QKV_ELEMS;
    float* vout = kout + QKV_ELEMS;

    const bool use_ws = ws_size >= ((size_t)N * M + 16) * sizeof(float);
    const int npos = (N / BR) * (M / BC);         // 128 tile positions

    if (use_ws) {
        float* pb      = (float*)d_ws;
        float* scale_p = pb + (size_t)N * M;
        const int ncopy = 3 * COPY_BLOCKS_PER;
        prep_kernel<<<dim3(PB_BLOCKS + ncopy + 1), dim3(256), 0, stream>>>(
            queries, keys, values, pos_enc, w_pos, b_pos, pb, scale_p,
            qout, kout, vout, ncopy);
        attn_kernel<<<dim3(npos, BH / BGROUP), dim3(256), 0, stream>>>(keys, pb, scale_p, out);
    } else {
        // Fallback: pb+scale in the q-region of d_out; copies after attn.
        float* pb      = qout;
        float* scale_p = pb + (size_t)N * M;
        prep_kernel<<<dim3(PB_BLOCKS + 1), dim3(256), 0, stream>>>(
            queries, keys, values, pos_enc, w_pos, b_pos, pb, scale_p,
            qout, kout, vout, /*ncopy=*/0);
        attn_kernel<<<dim3(npos, BH / BGROUP), dim3(256), 0, stream>>>(keys, pb, scale_p, out);
        hipMemcpyAsync(qout, queries, QKV_ELEMS * sizeof(float), hipMemcpyDeviceToDevice, stream);
        hipMemcpyAsync(kout, keys,    QKV_ELEMS * sizeof(float), hipMemcpyDeviceToDevice, stream);
        hipMemcpyAsync(vout, values,  QKV_ELEMS * sizeof(float), hipMemcpyDeviceToDevice, stream);
    }
}

// Round 6
// 206.168 us; speedup vs baseline: 1.3480x; 1.2432x over previous
//
#include <hip/hip_runtime.h>
#include <hip/hip_bf16.h>

typedef __attribute__((ext_vector_type(8))) short short8;
typedef __attribute__((ext_vector_type(4))) float f32x4;
typedef unsigned int u32;

constexpr int N = 1024, M = 1024, D = 64, BH = 128;
constexpr size_t ATTN_ELEMS = (size_t)BH * N * M;     // 134217728
constexpr size_t QKV_ELEMS  = (size_t)BH * N * D;     // 8388608
constexpr int PB_BLOCKS = 2048;
constexpr int KCONV_BLOCKS = 512;
constexpr int COPY_BLOCKS_PER = 256;                   // per q/k/v tensor
constexpr int BGROUP = 8;                              // batches per attn block
constexpr int BR = 32, BC = 256;                       // attn tile: 32 rows x 256 cols

__device__ __forceinline__ short f2b(float x) {
    __hip_bfloat16 h = __float2bfloat16(x);
    return *reinterpret_cast<short*>(&h);
}

__device__ __forceinline__ void gl_lds16(const void* g, void* l) {
    __builtin_amdgcn_global_load_lds(
        (const __attribute__((address_space(1))) u32*)g,
        (__attribute__((address_space(3))) u32*)l, 16, 0, 0);
}

// Fused prep:
//   [0, PB_BLOCKS)            : pb[n,m] = pos_enc[n,m,:].w + b
//   [.., +KCONV_BLOCKS)       : keys fp32 -> bf16, PRE-SWIZZLED slot order
//                               kbf[b][r][q] = bf16(keys[b][r][q ^ (r&7)])
//   [.., +ncopy)              : q/k/v pass-through copies
//   last                      : scale = sum(w)/sqrt(16)
__global__ void prep_kernel(const float* __restrict__ q, const float* __restrict__ k,
                            const float* __restrict__ v, const float* __restrict__ pos,
                            const float* __restrict__ w, const float* __restrict__ b,
                            float* __restrict__ pb, short* __restrict__ kbf,
                            float* __restrict__ scale_p,
                            float* __restrict__ qout, float* __restrict__ kout,
                            float* __restrict__ vout, int ncopy) {
    const int bid = blockIdx.x, tid = threadIdx.x;
    if (bid < PB_BLOCKS) {
        const int lane16 = tid & 15;
        const f32x4 w4 = ((const f32x4*)w)[lane16];
        const float bias = b[0];
        const int group = (bid * 256 + tid) >> 4;
        const int ngroups = (PB_BLOCKS * 256) >> 4;
        for (int pair = group; pair < N * M; pair += ngroups) {
            f32x4 p = __builtin_nontemporal_load((const f32x4*)pos + (size_t)pair * 16 + lane16);
            float s = p[0]*w4[0] + p[1]*w4[1] + p[2]*w4[2] + p[3]*w4[3];
            s += __shfl_xor(s, 1);
            s += __shfl_xor(s, 2);
            s += __shfl_xor(s, 4);
            s += __shfl_xor(s, 8);
            if (lane16 == 0) pb[pair] = s + bias;
        }
    } else if (bid < PB_BLOCKS + KCONV_BLOCKS) {
        const int cid = bid - PB_BLOCKS;
        const int total_slots = BH * N * 8;        // 16B slots, 1048576
        for (int gs = cid * 256 + tid; gs < total_slots; gs += KCONV_BLOCKS * 256) {
            const int qs = gs & 7, gr = (gs >> 3) & (N - 1), bb = gs >> 13;
            const float* src = k + ((size_t)bb * N + gr) * D + (qs ^ (gr & 7)) * 8;
            f32x4 x0 = ((const f32x4*)src)[0], x1 = ((const f32x4*)src)[1];
            short8 pk;
#pragma unroll
            for (int e = 0; e < 4; e++) { pk[e] = f2b(x0[e]); pk[4 + e] = f2b(x1[e]); }
            *(short8*)&kbf[(size_t)gs * 8] = pk;
        }
    } else if (bid < PB_BLOCKS + KCONV_BLOCKS + ncopy) {
        const int cid = bid - PB_BLOCKS - KCONV_BLOCKS;
        const int which = cid >> 8, lid = cid & 255;
        const f32x4* __restrict__ src = (which == 0) ? (const f32x4*)q
                                      : (which == 1) ? (const f32x4*)k : (const f32x4*)v;
        f32x4* __restrict__ dst = (which == 0) ? (f32x4*)qout
                                : (which == 1) ? (f32x4*)kout : (f32x4*)vout;
        const int nel4 = (int)(QKV_ELEMS / 4);
        for (int i = lid * 256 + tid; i < nel4; i += COPY_BLOCKS_PER * 256) {
            f32x4 x = __builtin_nontemporal_load(src + i);
            __builtin_nontemporal_store(x, dst + i);
        }
    } else {
        if (tid < 64) {
            float val = w[tid];
#pragma unroll
            for (int o = 32; o > 0; o >>= 1) val += __shfl_down(val, o);
            if (tid == 0) scale_p[0] = val * 0.25f;
        }
    }
}

// attn = (K K^T)*scale + pb.  32x256 tile (write locality), 4 waves (2x2: 16
// rows x 128 cols each), BGROUP batches per block, pb fragments in registers.
// Staging: global_load_lds width=16 straight from pre-swizzled bf16 keys —
// no VALU conversion, no register round-trip.  LDS 36KB, swizzled reads.
__launch_bounds__(256)
__global__ void attn_kernel(const short* __restrict__ kbf, const float* __restrict__ pb,
                            const float* __restrict__ scale_p, float* __restrict__ out) {
    __shared__ short lK[(BR + BC) * 64];
    const int pos = blockIdx.x;                   // 0..127
    const int tr = pos >> 2, tc = pos & 3;        // 32 row-tiles x 4 col-tiles
    const int batch0 = blockIdx.y * BGROUP;
    const int tid = threadIdx.x;
    const float scale = scale_p[0];

    const int lane = tid & 63, wv = tid >> 6;     // 4 waves
    const int wr = wv >> 1, wc = wv & 1;          // 2x2: 16 rows x 128 cols each
    const int frow = lane & 15;
    const int kslot = lane >> 4;

    const int orow = tr * BR + wr * 16 + (lane >> 4) * 4;   // + r
    const int ocol = tc * BC + wc * 128 + (lane & 15);      // + j*16

    // pb fragments in accumulator layout — reused for all BGROUP batches.
    f32x4 pf[8];
#pragma unroll
    for (int j = 0; j < 8; j++)
#pragma unroll
        for (int r = 0; r < 4; r++)
            pf[j][r] = pb[(size_t)(orow + r) * M + (ocol + j * 16)];

    for (int t = 0; t < BGROUP; ++t) {
        const short* __restrict__ Kb = kbf + (size_t)(batch0 + t) * N * 64;

        // Stage A rows [tr*32,+32) and B rows [tc*256,+256): 2304 16B slots,
        // direct global->LDS (source pre-swizzled, LDS linear).
#pragma unroll
        for (int it = 0; it < 9; ++it) {
            const int slot = it * 256 + tid;
            const int row = slot >> 3, qs = slot & 7;
            const int gr = (row < BR) ? (tr * BR + row) : (tc * BC + (row - BR));
            gl_lds16(Kb + (size_t)gr * 64 + qs * 8, &lK[slot * 8]);
        }
        __syncthreads();

        f32x4 acc[8] = {};
#pragma unroll
        for (int h = 0; h < 2; ++h) {             // k halves (k=0..31, 32..63)
            const int ra = wr * 16 + frow;
            short8 a = *(const short8*)&lK[ra * 64 + ((h * 4 + kslot) ^ (ra & 7)) * 8];
#pragma unroll
            for (int j = 0; j < 8; j++) {
                const int rb = BR + wc * 128 + j * 16 + frow;
                short8 bf = *(const short8*)&lK[rb * 64 + ((h * 4 + kslot) ^ (rb & 7)) * 8];
                acc[j] = __builtin_amdgcn_mfma_f32_16x16x32_bf16(a, bf, acc[j], 0, 0, 0);
            }
        }

        const size_t obase = (size_t)(batch0 + t) * N * M;
#pragma unroll
        for (int j = 0; j < 8; j++)
#pragma unroll
            for (int r = 0; r < 4; r++) {
                out[obase + (size_t)(orow + r) * M + (ocol + j * 16)]
                    = acc[j][r] * scale + pf[j][r];
            }
        __syncthreads();                          // LDS safe to overwrite next t
    }
}

extern "C" void kernel_launch(void* const* d_in, const int* in_sizes, int n_in,
                              void* d_out, int out_size, void* d_ws, size_t ws_size,
                              hipStream_t stream) {
    const float* queries = (const float*)d_in[0];
    const float* keys    = (const float*)d_in[1];
    const float* values  = (const float*)d_in[2];
    const float* pos_enc = (const float*)d_in[3];
    const float* w_pos   = (const float*)d_in[4];
    const float* b_pos   = (const float*)d_in[5];

    float* out  = (float*)d_out;
    float* qout = out + ATTN_ELEMS;
    float* kout = qout + QKV_ELEMS;
    float* vout = kout + QKV_ELEMS;

    // ws layout: pb (N*M floats) | scale (16 floats) | kbf (BH*N*64 shorts)
    const size_t need_ws = ((size_t)N * M + 16) * sizeof(float)
                         + (size_t)BH * N * 64 * sizeof(short);
    const int npos = (N / BR) * (M / BC);         // 128 tile positions

    if (ws_size >= need_ws) {
        float* pb      = (float*)d_ws;
        float* scale_p = pb + (size_t)N * M;
        short* kbf     = (short*)(scale_p + 16);
        const int ncopy = 3 * COPY_BLOCKS_PER;
        prep_kernel<<<dim3(PB_BLOCKS + KCONV_BLOCKS + ncopy + 1), dim3(256), 0, stream>>>(
            queries, keys, values, pos_enc, w_pos, b_pos, pb, kbf, scale_p,
            qout, kout, vout, ncopy);
        attn_kernel<<<dim3(npos, BH / BGROUP), dim3(256), 0, stream>>>(kbf, pb, scale_p, out);
    } else {
        // Fallback: stash pb + scale + kbf in the q/k region of d_out (20MB
        // < 64MB), run prep without copies, attn, then copy q/k/v after.
        float* pb      = qout;
        float* scale_p = pb + (size_t)N * M;
        short* kbf     = (short*)(scale_p + 16);
        prep_kernel<<<dim3(PB_BLOCKS + KCONV_BLOCKS + 1), dim3(256), 0, stream>>>(
            queries, keys, values, pos_enc, w_pos, b_pos, pb, kbf, scale_p,
            qout, kout, vout, /*ncopy=*/0);
        attn_kernel<<<dim3(npos, BH / BGROUP), dim3(256), 0, stream>>>(kbf, pb, scale_p, out);
        hipMemcpyAsync(qout, queries, QKV_ELEMS * sizeof(float), hipMemcpyDeviceToDevice, stream);
        hipMemcpyAsync(kout, keys,    QKV_ELEMS * sizeof(float), hipMemcpyDeviceToDevice, stream);
        hipMemcpyAsync(vout, values,  QKV_ELEMS * sizeof(float), hipMemcpyDeviceToDevice, stream);
    }
}